// Round 6
// baseline (2836.294 us; speedup 1.0000x reference)
//
#include <hip/hip_runtime.h>
#include <math.h>

#define B_ 4
#define S_ 2048
#define D_ 1024
#define H_ 2048
#define N_TOK 8192
#define HALO 256
#define VOCAB_ 32000

__device__ __forceinline__ float sigf(float x) {
  return 1.0f / (1.0f + __expf(-x));
}

// ---------------------------------------------------------------- gains (f64 tanh)
__global__ __launch_bounds__(256) void k_gains(const int* __restrict__ ids,
    const float* __restrict__ table, float* __restrict__ gains) {
  int i = blockIdx.x*256 + threadIdx.x;
  int id = ids[i];
  id = id < 0 ? 0 : (id >= VOCAB_ ? VOCAB_-1 : id);
  gains[i] = (float)(1.0 + tanh((double)table[id]));
}

// ---------------------------------------------------------------- f32 SIMT GEMM, f64-block accumulation
// acc[row,col] = sum_k A[row, k] * W[k, c0+col]   (A lda, W ldw row-major)
// mode 0: C = acc            (raw partial)
// mode 1: C += acc           (raw accumulate)
// mode 2: C = g*(C+acc)+b    (split-K finalize)
// mode 3: C = g*acc+b        (single-pass finalize)
// 128x128 tile, 256 threads, 8x8 per thread; grid (N/128, M/128)
__global__ __launch_bounds__(256) void k_genc(
    const float* __restrict__ A, int lda,
    const float* __restrict__ W, int ldw, int c0,
    const float* __restrict__ bias,
    const float* __restrict__ gains,
    float* __restrict__ C, int ldc,
    int K, int mode)
{
  __shared__ float As2[16][132];   // [k][row] (transposed), pad 132
  __shared__ float Bs[16][128];    // [k][col]
  const int tid = threadIdx.x;
  const int tx = tid & 15;
  const int ty = tid >> 4;
  const int bm = blockIdx.y * 128;
  const int bn = blockIdx.x * 128;

  double acc[8][8];
  float part[8][8];
  #pragma unroll
  for (int i = 0; i < 8; ++i)
    #pragma unroll
    for (int j = 0; j < 8; ++j) { acc[i][j] = 0.0; part[i][j] = 0.f; }

  const int e = tid * 8;
  const int ar = e >> 4, ak = e & 15;        // A: row 0..127, k 0 or 8
  const int bk = e >> 7, bc = e & 127;       // B: k 0..15, col mult of 8

  for (int k0 = 0; k0 < K; k0 += 16) {
    {
      const float* pa = A + (size_t)(bm + ar)*lda + k0 + ak;
      float4 v0 = *(const float4*)pa;
      float4 v1 = *(const float4*)(pa + 4);
      As2[ak+0][ar] = v0.x; As2[ak+1][ar] = v0.y;
      As2[ak+2][ar] = v0.z; As2[ak+3][ar] = v0.w;
      As2[ak+4][ar] = v1.x; As2[ak+5][ar] = v1.y;
      As2[ak+6][ar] = v1.z; As2[ak+7][ar] = v1.w;
    }
    {
      const float* pw = W + (size_t)(k0 + bk)*ldw + c0 + bn + bc;
      *(float4*)&Bs[bk][bc]   = *(const float4*)pw;
      *(float4*)&Bs[bk][bc+4] = *(const float4*)(pw + 4);
    }
    __syncthreads();
    #pragma unroll
    for (int kk = 0; kk < 16; ++kk) {
      float a8[8], b8[8];
      *(float4*)&a8[0] = *(const float4*)&As2[kk][ty*8];
      *(float4*)&a8[4] = *(const float4*)&As2[kk][ty*8+4];
      *(float4*)&b8[0] = *(const float4*)&Bs[kk][tx*8];
      *(float4*)&b8[4] = *(const float4*)&Bs[kk][tx*8+4];
      #pragma unroll
      for (int i = 0; i < 8; ++i)
        #pragma unroll
        for (int j = 0; j < 8; ++j)
          part[i][j] += a8[i]*b8[j];
    }
    __syncthreads();
    #pragma unroll
    for (int i = 0; i < 8; ++i)
      #pragma unroll
      for (int j = 0; j < 8; ++j) { acc[i][j] += (double)part[i][j]; part[i][j] = 0.f; }
  }

  #pragma unroll
  for (int i = 0; i < 8; ++i) {
    const int row = bm + ty*8 + i;
    const double g = (mode >= 2) ? (double)gains[row] : 0.0;
    #pragma unroll
    for (int j = 0; j < 8; ++j) {
      const int col = bn + tx*8 + j;
      const size_t idx = (size_t)row*ldc + col;
      if (mode == 0)      C[idx] = (float)acc[i][j];
      else if (mode == 1) C[idx] += (float)acc[i][j];
      else if (mode == 2) C[idx] = (float)(g*((double)C[idx] + acc[i][j]) + (double)bias[c0+col]);
      else                C[idx] = (float)(g*acc[i][j] + (double)bias[c0+col]);
    }
  }
}

// ---------------------------------------------------------------- GIF scan, f64 membrane, 256-halo chunks
// buf: [nb][Stot][Wd] f32 (nb = channels/Wd); grid (channels/256, chunks)
__global__ __launch_bounds__(256) void k_gif_warm(const float* __restrict__ buf,
    double* __restrict__ vinit, int Wd, int CS, int Stot)
{
  int c = blockIdx.x*256 + threadIdx.x;
  int channels = gridDim.x*256;
  int chunk = blockIdx.y;
  int b = c / Wd, h = c - b*Wd;
  int s_emit = chunk*CS;
  int s0 = s_emit - HALO; if (s0 < 0) s0 = 0;
  const float* p = buf + (size_t)b*Stot*Wd + h;
  double v = 0.0;
  for (int sg = s0; sg < s_emit; sg += 8) {
    float cv[8];
    #pragma unroll
    for (int i = 0; i < 8; ++i) cv[i] = p[(size_t)(sg+i)*Wd];
    #pragma unroll
    for (int i = 0; i < 8; ++i) {
      v = 0.9*v + (double)cv[i];
      double s = 1.0/(1.0 + exp(-4.0*(v - 1.0)));
      v -= s;
    }
  }
  vinit[(size_t)chunk*channels + c] = v;
}

__global__ __launch_bounds__(256) void k_gif_emit(float* __restrict__ buf,
    const double* __restrict__ vinit, int Wd, int CS, int Stot)
{
  int c = blockIdx.x*256 + threadIdx.x;
  int channels = gridDim.x*256;
  int chunk = blockIdx.y;
  int b = c / Wd, h = c - b*Wd;
  float* p = buf + (size_t)b*Stot*Wd + h + (size_t)chunk*CS*Wd;
  double v = vinit[(size_t)chunk*channels + c];
  float cv[8], nv[8] = {0,0,0,0,0,0,0,0};
  #pragma unroll
  for (int i = 0; i < 8; ++i) cv[i] = p[(size_t)i*Wd];
  for (int sg = 0; sg < CS; sg += 8) {
    float sp[8];
    #pragma unroll
    for (int i = 0; i < 8; ++i) {
      v = 0.9*v + (double)cv[i];
      double s = 1.0/(1.0 + exp(-4.0*(v - 1.0)));
      v -= s; sp[i] = (float)s;
    }
    if (sg + 8 < CS) {
      #pragma unroll
      for (int i = 0; i < 8; ++i) nv[i] = p[(size_t)(sg+8+i)*Wd];
    }
    #pragma unroll
    for (int i = 0; i < 8; ++i) p[(size_t)(sg+i)*Wd] = sp[i];
    #pragma unroll
    for (int i = 0; i < 8; ++i) cv[i] = nv[i];
  }
}

// ---------------------------------------------------------------- s2c partial, full-f64 FMA
// out[n,64] (+)= Sp[n,0:KH] @ W[woff..][0:KH,64]
__global__ __launch_bounds__(256) void k_s2c(const float* __restrict__ Sp, int KH,
    const float* __restrict__ W, size_t woff, float* __restrict__ out, int accum) {
  __shared__ float As_[64][17];
  __shared__ float Ws_[16][68];
  const int bm = blockIdx.x * 64;
  const int tid = threadIdx.x;
  const int rt = tid >> 4;
  const int ct = tid & 15;
  double acc[4][4] = {};
  for (int k0 = 0; k0 < KH; k0 += 16) {
    #pragma unroll
    for (int i = 0; i < 4; ++i) {
      int e = tid + i*256;
      As_[e >> 4][e & 15] = Sp[(size_t)(bm + (e >> 4))*KH + k0 + (e & 15)];
    }
    #pragma unroll
    for (int i = 0; i < 4; ++i) {
      int e = tid + i*256;
      Ws_[e >> 6][e & 63] = W[woff + (size_t)(k0 + (e >> 6))*64 + (e & 63)];
    }
    __syncthreads();
    #pragma unroll
    for (int kk = 0; kk < 16; ++kk) {
      double a4[4], b4[4];
      #pragma unroll
      for (int i = 0; i < 4; ++i) a4[i] = (double)As_[rt*4+i][kk];
      #pragma unroll
      for (int j = 0; j < 4; ++j) b4[j] = (double)Ws_[kk][ct*4+j];
      #pragma unroll
      for (int i = 0; i < 4; ++i)
        #pragma unroll
        for (int j = 0; j < 4; ++j) acc[i][j] += a4[i]*b4[j];
    }
    __syncthreads();
  }
  #pragma unroll
  for (int i = 0; i < 4; ++i)
    #pragma unroll
    for (int j = 0; j < 4; ++j) {
      size_t idx = ((size_t)bm + rt*4+i)*64 + ct*4+j;
      float a = (float)acc[i][j];
      if (accum) out[idx] += a; else out[idx] = a;
    }
}

// ---------------------------------------------------------------- router: f64 logits, total top-2
__global__ __launch_bounds__(256) void k_router(float* __restrict__ contp,
    const float* __restrict__ s2c_b,
    const float* __restrict__ rW1, const float* __restrict__ rb1,
    const float* __restrict__ rW2, const float* __restrict__ rb2,
    const float* __restrict__ gains,
    int* __restrict__ topi, float* __restrict__ topw)
{
  __shared__ float W1s[64*64];
  __shared__ float W2s[64*8];
  __shared__ float b1s[64];
  __shared__ float b2s[8];
  __shared__ float sbl[64];
  const int tid = threadIdx.x;
  const int n = blockIdx.x*256 + tid;
  for (int i = tid; i < 64*64; i += 256) W1s[i] = rW1[i];
  for (int i = tid; i < 64*8; i += 256)  W2s[i] = rW2[i];
  if (tid < 64) { b1s[tid] = rb1[tid]; sbl[tid] = s2c_b[tid]; }
  if (tid < 8)  b2s[tid] = rb2[tid];
  __syncthreads();

  float c[64];
  {
    float4* pA = (float4*)(contp + (size_t)n*64);
    #pragma unroll
    for (int m4 = 0; m4 < 16; ++m4) {
      float4 a = pA[m4];
      float4 o;
      o.x = a.x + sbl[m4*4+0];
      o.y = a.y + sbl[m4*4+1];
      o.z = a.z + sbl[m4*4+2];
      o.w = a.w + sbl[m4*4+3];
      c[m4*4+0] = o.x; c[m4*4+1] = o.y; c[m4*4+2] = o.z; c[m4*4+3] = o.w;
      pA[m4] = o;   // biased cont, in place (row-local)
    }
  }
  double lg[8];
  #pragma unroll
  for (int e = 0; e < 8; ++e) lg[e] = (double)b2s[e];
  for (int j = 0; j < 64; ++j) {
    double t = (double)b1s[j];
    #pragma unroll
    for (int m = 0; m < 64; ++m) t += (double)c[m]*(double)W1s[m*64 + j];
    t = tanh(t);
    #pragma unroll
    for (int e = 0; e < 8; ++e) lg[e] += t * (double)W2s[j*8 + e];
  }
  double g = (double)gains[n];
  #pragma unroll
  for (int e = 0; e < 8; ++e) lg[e] *= g;
  int i1 = 0; double m1 = lg[0];
  #pragma unroll
  for (int e = 1; e < 8; ++e) if (lg[e] > m1) { m1 = lg[e]; i1 = e; }
  int i2 = (i1 == 0) ? 1 : 0; double m2 = lg[i2];
  #pragma unroll
  for (int e = 0; e < 8; ++e) if (e != i1 && lg[e] > m2) { m2 = lg[e]; i2 = e; }
  float w1 = (float)(1.0 / (1.0 + exp(m2 - m1)));
  topi[(size_t)n*2 + 0] = i1; topi[(size_t)n*2 + 1] = i2;
  topw[(size_t)n*2 + 0] = w1; topw[(size_t)n*2 + 1] = 1.0f - w1;
}

// ---------------------------------------------------------------- experts (f32, top-2 only)
__global__ __launch_bounds__(256) void k_experts(const float* __restrict__ cont,
    const int* __restrict__ topi, const float* __restrict__ topw,
    const float* __restrict__ eW1, const float* __restrict__ eb1,
    const float* __restrict__ eW2, const float* __restrict__ eb2,
    float* __restrict__ moe)
{
  __shared__ float cl[64];
  __shared__ float hl[1024];
  __shared__ float red[4][64];
  __shared__ float macc[64];
  const int tid = threadIdx.x;
  const int n = blockIdx.x;
  if (tid < 64) { cl[tid] = cont[(size_t)n*64 + tid]; macc[tid] = 0.f; }
  __syncthreads();
  #pragma unroll
  for (int k = 0; k < 2; ++k) {
    const int e = topi[(size_t)n*2 + k] & 7;
    const float w = topw[(size_t)n*2 + k];
    float hacc[4];
    #pragma unroll
    for (int i = 0; i < 4; ++i) hacc[i] = eb1[(size_t)e*1024 + tid*4 + i];
    const float* W1f = eW1 + (size_t)e*64*1024 + tid*4;
    for (int m = 0; m < 64; ++m) {
      float cm = cl[m];
      float4 wv = *(const float4*)(W1f + (size_t)m*1024);
      hacc[0] += cm * wv.x; hacc[1] += cm * wv.y;
      hacc[2] += cm * wv.z; hacc[3] += cm * wv.w;
    }
    #pragma unroll
    for (int i = 0; i < 4; ++i) hl[tid*4+i] = fmaxf(hacc[i], 0.f);
    __syncthreads();
    const float* W2f = eW2 + (size_t)e*1024*64;
    const int m = tid & 63, part = tid >> 6;
    float s = 0.f;
    for (int hh = part*256; hh < part*256 + 256; ++hh)
      s += hl[hh] * W2f[(size_t)hh*64 + m];
    red[part][m] = s;
    __syncthreads();
    if (tid < 64) {
      float tot = red[0][tid] + red[1][tid] + red[2][tid] + red[3][tid]
                + eb2[(size_t)e*64 + tid];
      macc[tid] += w * tot;
    }
    __syncthreads();
  }
  if (tid < 64) moe[(size_t)n*64 + tid] = macc[tid];
}

// ---------------------------------------------------------------- c2s 256-col slice -> f32 rates
// rat[nl][256] = sigmoid(moe8[nl] @ c2s_W[:, coff..coff+256) + b[coff..])
__global__ __launch_bounds__(256) void k_c2sS(const float* __restrict__ moe8,
    const float* __restrict__ W, int coff,
    const float* __restrict__ bias, float* __restrict__ rat)
{
  __shared__ float ml[8][64];
  const int tid = threadIdx.x;
  const int n0 = blockIdx.x * 8;
  for (int i = tid; i < 512; i += 256) ml[i >> 6][i & 63] = moe8[(size_t)n0*64 + i];
  __syncthreads();
  float acc[8] = {};
  for (int m = 0; m < 64; ++m) {
    float wv = W[(size_t)m*H_ + coff + tid];
    #pragma unroll
    for (int t = 0; t < 8; ++t) acc[t] += ml[t][m] * wv;
  }
  float bv = bias[coff + tid];
  #pragma unroll
  for (int t = 0; t < 8; ++t)
    rat[(size_t)(n0+t)*256 + tid] = sigf(acc[t] + bv);
}

// ---------------------------------------------------------------- layernorm D=1024, f32 in/out, safe in-place
__global__ __launch_bounds__(256) void k_ln(float* __restrict__ X,
    const float* __restrict__ g, const float* __restrict__ b)
{
  const int n = blockIdx.x, tid = threadIdx.x;
  float4* row = (float4*)(X + (size_t)n*D_);
  const float4 xv = row[tid];
  float xa[4] = {xv.x, xv.y, xv.z, xv.w};
  float s = xa[0]+xa[1]+xa[2]+xa[3];
  float ss = xa[0]*xa[0]+xa[1]*xa[1]+xa[2]*xa[2]+xa[3]*xa[3];
  #pragma unroll
  for (int off = 32; off >= 1; off >>= 1) {
    s  += __shfl_down(s, off);
    ss += __shfl_down(ss, off);
  }
  __shared__ float rs[4], rss[4];
  const int lane = tid & 63, wv = tid >> 6;
  if (lane == 0) { rs[wv] = s; rss[wv] = ss; }
  __syncthreads();
  float S0 = rs[0]+rs[1]+rs[2]+rs[3];
  float SS = rss[0]+rss[1]+rss[2]+rss[3];
  float mu = S0 * (1.f/(float)D_);
  float var = SS * (1.f/(float)D_) - mu*mu;
  float inv = rsqrtf(var + 1e-5f);
  int idx = tid*4;
  float4 o;
  o.x = (xa[0]-mu)*inv*g[idx+0] + b[idx+0];
  o.y = (xa[1]-mu)*inv*g[idx+1] + b[idx+1];
  o.z = (xa[2]-mu)*inv*g[idx+2] + b[idx+2];
  o.w = (xa[3]-mu)*inv*g[idx+3] + b[idx+3];
  row[tid] = o;   // in-place safe: each thread rewrites only what it read
}

// ----------------------------------------------------------------
// All-f32 dataset (established R4/R5: structured error under f32 reads, f32
// 32 MiB out writes succeeded). ws total 6.3 MiB (proven-safe <=12.6):
//   0x000000 contp/cont/moe f32[8192][64]  (aliased, row-local ops)
//   0x200000 ratSf f32[4096][256]          (dec K-slice)
//   0x600000 gains 32K | 0x608000 topi 64K | 0x618000 topw 64K
//   0x628000 vinit double[16384] 128K
// d_out (f32 [8192][1024], 32 MiB):
//   enc phase: cur f32[8192][512] in [0,16M), reused 4x (H-chunks)
//   dec phase: cur2 f32[4096][1024] per hb at hb*16M; LN in place.
extern "C" void kernel_launch(void* const* d_in, const int* in_sizes, int n_in,
                              void* d_out, int out_size, void* d_ws, size_t ws_size,
                              hipStream_t stream) {
  (void)in_sizes; (void)n_in; (void)out_size; (void)ws_size;
  const float* embeds = (const float*)d_in[0];
  const int*   ids    = (const int*)d_in[1];
  const float* pros   = (const float*)d_in[2];
  const float* enc_W  = (const float*)d_in[3];
  const float* enc_b  = (const float*)d_in[4];
  const float* s2c_W  = (const float*)d_in[5];
  const float* s2c_b  = (const float*)d_in[6];
  const float* r_W1   = (const float*)d_in[7];
  const float* r_b1   = (const float*)d_in[8];
  const float* r_W2   = (const float*)d_in[9];
  const float* r_b2   = (const float*)d_in[10];
  const float* e_W1   = (const float*)d_in[11];
  const float* e_b1   = (const float*)d_in[12];
  const float* e_W2   = (const float*)d_in[13];
  const float* e_b2   = (const float*)d_in[14];
  const float* c2s_W  = (const float*)d_in[15];
  const float* c2s_b  = (const float*)d_in[16];
  const float* dec_W  = (const float*)d_in[17];
  const float* dec_b  = (const float*)d_in[18];
  const float* ln_g   = (const float*)d_in[19];
  const float* ln_b   = (const float*)d_in[20];

  char* ws = (char*)d_ws;
  float*  contp = (float*)ws;                            // 2 MiB, aliases cont/moe
  float*  cont  = contp;
  float*  moe   = contp;
  float*  ratSf = (float*)(ws + (size_t)0x200000);       // 4 MiB
  float*  gains = (float*)(ws + (size_t)0x600000);       // 32 KiB
  int*    topi  = (int*)(ws + (size_t)0x608000);         // 64 KiB
  float*  topw  = (float*)(ws + (size_t)0x618000);       // 64 KiB
  double* vinit = (double*)(ws + (size_t)0x628000);      // 128 KiB
  float*  cur   = (float*)d_out;                         // enc scratch [8192][512]

  k_gains<<<N_TOK/256, 256, 0, stream>>>(ids, pros, gains);

  // ---- encoder: 4 H-chunks of 512, all-f32 exact ----
  for (int c = 0; c < 4; ++c) {
    k_genc<<<dim3(4, 64), 256, 0, stream>>>(
        embeds, D_, enc_W, H_, c*512, enc_b, gains, cur, 512, D_, 3);
    k_gif_warm<<<dim3(8, 8), 256, 0, stream>>>(cur, vinit, 512, 256, S_);
    k_gif_emit<<<dim3(8, 8), 256, 0, stream>>>(cur, vinit, 512, 256, S_);
    k_s2c<<<N_TOK/64, 256, 0, stream>>>(cur, 512, s2c_W, (size_t)c*512*64, contp, (c > 0));
  }

  k_router<<<N_TOK/256, 256, 0, stream>>>(contp, s2c_b, r_W1, r_b1, r_W2, r_b2,
                                          gains, topi, topw);
  k_experts<<<N_TOK, 256, 0, stream>>>(cont, topi, topw, e_W1, e_b1, e_W2, e_b2, moe);

  // ---- decoder: 2 halves of 4096 tokens (full batches -> no carry), K-sliced 8x256 ----
  for (int hb = 0; hb < 2; ++hb) {
    float* cur2 = (float*)d_out + (size_t)hb*4096*D_;
    for (int kh = 0; kh < 8; ++kh) {
      k_c2sS<<<4096/8, 256, 0, stream>>>(moe + (size_t)hb*4096*64,
          c2s_W, kh*256, c2s_b, ratSf);
      int mode = (kh == 0) ? 0 : ((kh < 7) ? 1 : 2);
      k_genc<<<dim3(8, 32), 256, 0, stream>>>(
          ratSf, 256, dec_W + (size_t)kh*256*D_, D_, 0, dec_b,
          gains + hb*4096, cur2, D_, 256, mode);
    }
    k_gif_warm<<<dim3(8, 8), 256, 0, stream>>>(cur2, vinit, D_, 256, S_);
    k_gif_emit<<<dim3(8, 8), 256, 0, stream>>>(cur2, vinit, D_, 256, S_);
    k_ln<<<4096, 256, 0, stream>>>(cur2, ln_g, ln_b);
  }
}

// Round 7
// 1644.553 us; speedup vs baseline: 1.7247x; 1.7247x over previous
//
#include <hip/hip_runtime.h>
#include <math.h>

#define B_ 4
#define S_ 2048
#define D_ 1024
#define H_ 2048
#define N_TOK 8192
#define HALO 256
#define VOCAB_ 32000

typedef short bf16x8 __attribute__((ext_vector_type(8)));
typedef float f32x4 __attribute__((ext_vector_type(4)));

__device__ __forceinline__ float sigf(float x) {
  return 1.0f / (1.0f + __expf(-x));
}
__device__ __forceinline__ unsigned short f2bf(float f) {
  union { float f; unsigned int i; } x; x.f = f;
  unsigned int r = x.i + 0x7fffu + ((x.i >> 16) & 1u);
  return (unsigned short)(r >> 16);
}

// ---------------------------------------------------------------- gains (f64 tanh) — identical to R6
__global__ __launch_bounds__(256) void k_gains(const int* __restrict__ ids,
    const float* __restrict__ table, float* __restrict__ gains) {
  int i = blockIdx.x*256 + threadIdx.x;
  int id = ids[i];
  id = id < 0 ? 0 : (id >= VOCAB_ ? VOCAB_-1 : id);
  gains[i] = (float)(1.0 + tanh((double)table[id]));
}

// ---------------------------------------------------------------- f32 SIMT GEMM, f64-block accumulation — identical math to R6
__global__ __launch_bounds__(256) void k_genc(
    const float* __restrict__ A, int lda,
    const float* __restrict__ W, int ldw, int c0,
    const float* __restrict__ bias,
    const float* __restrict__ gains,
    float* __restrict__ C, int ldc,
    int K, int mode)
{
  __shared__ float As2[16][132];
  __shared__ float Bs[16][128];
  const int tid = threadIdx.x;
  const int tx = tid & 15;
  const int ty = tid >> 4;
  const int bm = blockIdx.y * 128;
  const int bn = blockIdx.x * 128;

  double acc[8][8];
  float part[8][8];
  #pragma unroll
  for (int i = 0; i < 8; ++i)
    #pragma unroll
    for (int j = 0; j < 8; ++j) { acc[i][j] = 0.0; part[i][j] = 0.f; }

  const int e = tid * 8;
  const int ar = e >> 4, ak = e & 15;
  const int bk = e >> 7, bc = e & 127;

  for (int k0 = 0; k0 < K; k0 += 16) {
    {
      const float* pa = A + (size_t)(bm + ar)*lda + k0 + ak;
      float4 v0 = *(const float4*)pa;
      float4 v1 = *(const float4*)(pa + 4);
      As2[ak+0][ar] = v0.x; As2[ak+1][ar] = v0.y;
      As2[ak+2][ar] = v0.z; As2[ak+3][ar] = v0.w;
      As2[ak+4][ar] = v1.x; As2[ak+5][ar] = v1.y;
      As2[ak+6][ar] = v1.z; As2[ak+7][ar] = v1.w;
    }
    {
      const float* pw = W + (size_t)(k0 + bk)*ldw + c0 + bn + bc;
      *(float4*)&Bs[bk][bc]   = *(const float4*)pw;
      *(float4*)&Bs[bk][bc+4] = *(const float4*)(pw + 4);
    }
    __syncthreads();
    #pragma unroll
    for (int kk = 0; kk < 16; ++kk) {
      float a8[8], b8[8];
      *(float4*)&a8[0] = *(const float4*)&As2[kk][ty*8];
      *(float4*)&a8[4] = *(const float4*)&As2[kk][ty*8+4];
      *(float4*)&b8[0] = *(const float4*)&Bs[kk][tx*8];
      *(float4*)&b8[4] = *(const float4*)&Bs[kk][tx*8+4];
      #pragma unroll
      for (int i = 0; i < 8; ++i)
        #pragma unroll
        for (int j = 0; j < 8; ++j)
          part[i][j] += a8[i]*b8[j];
    }
    __syncthreads();
    #pragma unroll
    for (int i = 0; i < 8; ++i)
      #pragma unroll
      for (int j = 0; j < 8; ++j) { acc[i][j] += (double)part[i][j]; part[i][j] = 0.f; }
  }

  #pragma unroll
  for (int i = 0; i < 8; ++i) {
    const int row = bm + ty*8 + i;
    const double g = (mode >= 2) ? (double)gains[row] : 0.0;
    #pragma unroll
    for (int j = 0; j < 8; ++j) {
      const int col = bn + tx*8 + j;
      const size_t idx = (size_t)row*ldc + col;
      if (mode == 0)      C[idx] = (float)acc[i][j];
      else if (mode == 1) C[idx] += (float)acc[i][j];
      else if (mode == 2) C[idx] = (float)(g*((double)C[idx] + acc[i][j]) + (double)bias[c0+col]);
      else                C[idx] = (float)(g*acc[i][j] + (double)bias[c0+col]);
    }
  }
}

// ---------------------------------------------------------------- GIF scan, f64 membrane — identical math to R6
__global__ __launch_bounds__(256) void k_gif_warm(const float* __restrict__ buf,
    double* __restrict__ vinit, int Wd, int CS, int Stot)
{
  int c = blockIdx.x*256 + threadIdx.x;
  int channels = gridDim.x*256;
  int chunk = blockIdx.y;
  int b = c / Wd, h = c - b*Wd;
  int s_emit = chunk*CS;
  int s0 = s_emit - HALO; if (s0 < 0) s0 = 0;
  const float* p = buf + (size_t)b*Stot*Wd + h;
  double v = 0.0;
  for (int sg = s0; sg < s_emit; sg += 8) {
    float cv[8];
    #pragma unroll
    for (int i = 0; i < 8; ++i) cv[i] = p[(size_t)(sg+i)*Wd];
    #pragma unroll
    for (int i = 0; i < 8; ++i) {
      v = 0.9*v + (double)cv[i];
      double s = 1.0/(1.0 + exp(-4.0*(v - 1.0)));
      v -= s;
    }
  }
  vinit[(size_t)chunk*channels + c] = v;
}

__global__ __launch_bounds__(256) void k_gif_emit(float* __restrict__ buf,
    const double* __restrict__ vinit, int Wd, int CS, int Stot)
{
  int c = blockIdx.x*256 + threadIdx.x;
  int channels = gridDim.x*256;
  int chunk = blockIdx.y;
  int b = c / Wd, h = c - b*Wd;
  float* p = buf + (size_t)b*Stot*Wd + h + (size_t)chunk*CS*Wd;
  double v = vinit[(size_t)chunk*channels + c];
  float cv[8], nv[8] = {0,0,0,0,0,0,0,0};
  #pragma unroll
  for (int i = 0; i < 8; ++i) cv[i] = p[(size_t)i*Wd];
  for (int sg = 0; sg < CS; sg += 8) {
    float sp[8];
    #pragma unroll
    for (int i = 0; i < 8; ++i) {
      v = 0.9*v + (double)cv[i];
      double s = 1.0/(1.0 + exp(-4.0*(v - 1.0)));
      v -= s; sp[i] = (float)s;
    }
    if (sg + 8 < CS) {
      #pragma unroll
      for (int i = 0; i < 8; ++i) nv[i] = p[(size_t)(sg+8+i)*Wd];
    }
    #pragma unroll
    for (int i = 0; i < 8; ++i) p[(size_t)(sg+i)*Wd] = sp[i];
    #pragma unroll
    for (int i = 0; i < 8; ++i) cv[i] = nv[i];
  }
}

// ---------------------------------------------------------------- s2c partial, f64 FMA — same math as R6, + row stride param
__global__ __launch_bounds__(256) void k_s2c(const float* __restrict__ Sp, int ldS, int KH,
    const float* __restrict__ W, size_t woff, float* __restrict__ out, int accum) {
  __shared__ float As_[64][17];
  __shared__ float Ws_[16][68];
  const int bm = blockIdx.x * 64;
  const int tid = threadIdx.x;
  const int rt = tid >> 4;
  const int ct = tid & 15;
  double acc[4][4] = {};
  for (int k0 = 0; k0 < KH; k0 += 16) {
    #pragma unroll
    for (int i = 0; i < 4; ++i) {
      int e = tid + i*256;
      As_[e >> 4][e & 15] = Sp[(size_t)(bm + (e >> 4))*ldS + k0 + (e & 15)];
    }
    #pragma unroll
    for (int i = 0; i < 4; ++i) {
      int e = tid + i*256;
      Ws_[e >> 6][e & 63] = W[woff + (size_t)(k0 + (e >> 6))*64 + (e & 63)];
    }
    __syncthreads();
    #pragma unroll
    for (int kk = 0; kk < 16; ++kk) {
      double a4[4], b4[4];
      #pragma unroll
      for (int i = 0; i < 4; ++i) a4[i] = (double)As_[rt*4+i][kk];
      #pragma unroll
      for (int j = 0; j < 4; ++j) b4[j] = (double)Ws_[kk][ct*4+j];
      #pragma unroll
      for (int i = 0; i < 4; ++i)
        #pragma unroll
        for (int j = 0; j < 4; ++j) acc[i][j] += a4[i]*b4[j];
    }
    __syncthreads();
  }
  #pragma unroll
  for (int i = 0; i < 4; ++i)
    #pragma unroll
    for (int j = 0; j < 4; ++j) {
      size_t idx = ((size_t)bm + rt*4+i)*64 + ct*4+j;
      float a = (float)acc[i][j];
      if (accum) out[idx] += a; else out[idx] = a;
    }
}

// ---------------------------------------------------------------- zero expert counters
__global__ void k_zero(int* p) { if (threadIdx.x < 8) p[threadIdx.x] = 0; }

// ---------------------------------------------------------------- router: f64 logits (identical to R6) + per-expert list append
__global__ __launch_bounds__(256) void k_router(float* __restrict__ contp,
    const float* __restrict__ s2c_b,
    const float* __restrict__ rW1, const float* __restrict__ rb1,
    const float* __restrict__ rW2, const float* __restrict__ rb2,
    const float* __restrict__ gains,
    int* __restrict__ cnt, unsigned int* __restrict__ list, float* __restrict__ lw)
{
  __shared__ float W1s[64*64];
  __shared__ float W2s[64*8];
  __shared__ float b1s[64];
  __shared__ float b2s[8];
  __shared__ float sbl[64];
  const int tid = threadIdx.x;
  const int n = blockIdx.x*256 + tid;
  for (int i = tid; i < 64*64; i += 256) W1s[i] = rW1[i];
  for (int i = tid; i < 64*8; i += 256)  W2s[i] = rW2[i];
  if (tid < 64) { b1s[tid] = rb1[tid]; sbl[tid] = s2c_b[tid]; }
  if (tid < 8)  b2s[tid] = rb2[tid];
  __syncthreads();

  float c[64];
  {
    float4* pA = (float4*)(contp + (size_t)n*64);
    #pragma unroll
    for (int m4 = 0; m4 < 16; ++m4) {
      float4 a = pA[m4];
      float4 o;
      o.x = a.x + sbl[m4*4+0];
      o.y = a.y + sbl[m4*4+1];
      o.z = a.z + sbl[m4*4+2];
      o.w = a.w + sbl[m4*4+3];
      c[m4*4+0] = o.x; c[m4*4+1] = o.y; c[m4*4+2] = o.z; c[m4*4+3] = o.w;
      pA[m4] = o;
    }
  }
  double lg[8];
  #pragma unroll
  for (int e = 0; e < 8; ++e) lg[e] = (double)b2s[e];
  for (int j = 0; j < 64; ++j) {
    double t = (double)b1s[j];
    #pragma unroll
    for (int m = 0; m < 64; ++m) t += (double)c[m]*(double)W1s[m*64 + j];
    t = tanh(t);
    #pragma unroll
    for (int e = 0; e < 8; ++e) lg[e] += t * (double)W2s[j*8 + e];
  }
  double g = (double)gains[n];
  #pragma unroll
  for (int e = 0; e < 8; ++e) lg[e] *= g;
  int i1 = 0; double m1 = lg[0];
  #pragma unroll
  for (int e = 1; e < 8; ++e) if (lg[e] > m1) { m1 = lg[e]; i1 = e; }
  int i2 = (i1 == 0) ? 1 : 0; double m2 = lg[i2];
  #pragma unroll
  for (int e = 0; e < 8; ++e) if (e != i1 && lg[e] > m2) { m2 = lg[e]; i2 = e; }
  float w1 = (float)(1.0 / (1.0 + exp(m2 - m1)));
  // append to expert lists (slot packed: (token<<1)|k)
  int p1 = atomicAdd(&cnt[i1], 1);
  list[i1*8192 + p1] = ((unsigned)n << 1);
  lw[i1*8192 + p1] = w1;
  int p2 = atomicAdd(&cnt[i2], 1);
  list[i2*8192 + p2] = ((unsigned)n << 1) | 1u;
  lw[i2*8192 + p2] = 1.0f - w1;
}

// ---------------------------------------------------------------- grouped experts: 64 tokens of one expert per block
// eout[(token*2+k)*64 + n] = w * (relu(cont@W1e+b1e) @ W2e + b2e)[n]  — every slot written exactly once
__global__ __launch_bounds__(256) void k_expgrp(
    const float* __restrict__ cont,
    const unsigned int* __restrict__ list, const float* __restrict__ lw,
    const int* __restrict__ cnt,
    const float* __restrict__ eW1, const float* __restrict__ eb1,
    const float* __restrict__ eW2, const float* __restrict__ eb2,
    float* __restrict__ eout)
{
  const int e = blockIdx.y;
  const int t0 = blockIdx.x * 64;
  const int ce = cnt[e];
  if (t0 >= ce) return;
  const int nt = (ce - t0 < 64) ? (ce - t0) : 64;
  __shared__ float ct[64][65];
  __shared__ float w1b[64][65];
  __shared__ float hbl[64][65];
  __shared__ float w2b[64][65];
  __shared__ unsigned int sl[64];
  __shared__ float swt[64];
  const int tid = threadIdx.x;
  if (tid < 64) {
    if (tid < nt) {
      sl[tid]  = list[e*8192 + t0 + tid];
      swt[tid] = lw[e*8192 + t0 + tid];
    } else { sl[tid] = 0; swt[tid] = 0.f; }
  }
  __syncthreads();
  for (int f = tid; f < 64*64; f += 256) {
    int r = f >> 6, m = f & 63;
    ct[r][m] = (r < nt) ? cont[(size_t)(sl[r] >> 1)*64 + m] : 0.f;
  }
  const float* W1 = eW1 + (size_t)e*64*1024;
  const float* W2 = eW2 + (size_t)e*1024*64;
  const float* B1 = eb1 + (size_t)e*1024;
  const int rt = tid >> 4, c16 = tid & 15;
  float outa[4][4] = {};
  for (int hc = 0; hc < 1024; hc += 64) {
    __syncthreads();
    for (int f = tid; f < 64*64; f += 256) {
      int m = f >> 6, j = f & 63;
      w1b[m][j] = W1[(size_t)m*1024 + hc + j];
      w2b[m][j] = W2[(size_t)(hc + m)*64 + j];
    }
    __syncthreads();
    // GEMM1: h = relu(ct @ w1b + b1)
    float h4[4][4];
    #pragma unroll
    for (int i = 0; i < 4; ++i) {
      #pragma unroll
      for (int j = 0; j < 4; ++j) h4[i][j] = B1[hc + c16*4 + j];
    }
    #pragma unroll 16
    for (int m = 0; m < 64; ++m) {
      float a4[4], b4[4];
      #pragma unroll
      for (int i = 0; i < 4; ++i) a4[i] = ct[rt*4+i][m];
      #pragma unroll
      for (int j = 0; j < 4; ++j) b4[j] = w1b[m][c16*4+j];
      #pragma unroll
      for (int i = 0; i < 4; ++i)
        #pragma unroll
        for (int j = 0; j < 4; ++j) h4[i][j] += a4[i]*b4[j];
    }
    #pragma unroll
    for (int i = 0; i < 4; ++i)
      #pragma unroll
      for (int j = 0; j < 4; ++j)
        hbl[rt*4+i][c16*4+j] = fmaxf(h4[i][j], 0.f);
    __syncthreads();
    // GEMM2: outa += hbl @ w2b
    #pragma unroll 16
    for (int j = 0; j < 64; ++j) {
      float a4[4], b4[4];
      #pragma unroll
      for (int i = 0; i < 4; ++i) a4[i] = hbl[rt*4+i][j];
      #pragma unroll
      for (int nn = 0; nn < 4; ++nn) b4[nn] = w2b[j][c16*4+nn];
      #pragma unroll
      for (int i = 0; i < 4; ++i)
        #pragma unroll
        for (int nn = 0; nn < 4; ++nn) outa[i][nn] += a4[i]*b4[nn];
    }
  }
  #pragma unroll
  for (int i = 0; i < 4; ++i) {
    int r = rt*4 + i;
    if (r < nt) {
      float w = swt[r];
      #pragma unroll
      for (int nn = 0; nn < 4; ++nn) {
        int col = c16*4 + nn;
        eout[(size_t)sl[r]*64 + col] = w * (outa[i][nn] + eb2[(size_t)e*64 + col]);
      }
    }
  }
}

// ---------------------------------------------------------------- c2s -> bf16 rates (path A); moe row = slot0+slot1
__global__ __launch_bounds__(256) void k_c2sB(const float* __restrict__ eoutTok,
    const float* __restrict__ W, const float* __restrict__ bias,
    unsigned short* __restrict__ rates)
{
  __shared__ float ml[8][64];
  const int tid = threadIdx.x;
  const int n0 = blockIdx.x * 8;
  const int coff = blockIdx.y * 256;
  for (int i = tid; i < 512; i += 256) {
    int t = i >> 6, m = i & 63;
    ml[t][m] = eoutTok[(size_t)(n0+t)*128 + m] + eoutTok[(size_t)(n0+t)*128 + 64 + m];
  }
  __syncthreads();
  float acc[8] = {};
  for (int m = 0; m < 64; ++m) {
    float wv = W[(size_t)m*H_ + coff + tid];
    #pragma unroll
    for (int t = 0; t < 8; ++t) acc[t] += ml[t][m] * wv;
  }
  float bv = bias[coff + tid];
  #pragma unroll
  for (int t = 0; t < 8; ++t)
    rates[(size_t)(n0+t)*H_ + coff + tid] = f2bf(sigf(acc[t] + bv));
}

// ---------------------------------------------------------------- c2s 256-col slice -> f32 (fallback path)
__global__ __launch_bounds__(256) void k_c2sS(const float* __restrict__ eoutTok,
    const float* __restrict__ W, int coff,
    const float* __restrict__ bias, float* __restrict__ rat)
{
  __shared__ float ml[8][64];
  const int tid = threadIdx.x;
  const int n0 = blockIdx.x * 8;
  for (int i = tid; i < 512; i += 256) {
    int t = i >> 6, m = i & 63;
    ml[t][m] = eoutTok[(size_t)(n0+t)*128 + m] + eoutTok[(size_t)(n0+t)*128 + 64 + m];
  }
  __syncthreads();
  float acc[8] = {};
  for (int m = 0; m < 64; ++m) {
    float wv = W[(size_t)m*H_ + coff + tid];
    #pragma unroll
    for (int t = 0; t < 8; ++t) acc[t] += ml[t][m] * wv;
  }
  float bv = bias[coff + tid];
  #pragma unroll
  for (int t = 0; t < 8; ++t)
    rat[(size_t)(n0+t)*256 + tid] = sigf(acc[t] + bv);
}

// ---------------------------------------------------------------- f32 -> bf16 transpose (dec_W [R][C] -> out [C][R])
__global__ __launch_bounds__(256) void k_transb(const float* __restrict__ in,
    unsigned short* __restrict__ out, int R, int C) {
  __shared__ unsigned short t[32][33];
  int c0 = blockIdx.x*32, r0 = blockIdx.y*32;
  int tx = threadIdx.x & 31, ty = threadIdx.x >> 5;
  #pragma unroll
  for (int i = 0; i < 32; i += 8)
    t[ty+i][tx] = f2bf(in[(size_t)(r0+ty+i)*C + (c0+tx)]);
  __syncthreads();
  #pragma unroll
  for (int i = 0; i < 32; i += 8)
    out[(size_t)(c0+ty+i)*R + (r0+tx)] = t[tx][ty+i];
}

// ---------------------------------------------------------------- dec MFMA GEMM: C[M,1024] = gains[m]*(A[M,2048]bf16 @ BT[1024,2048]^T) + bias
__global__ __launch_bounds__(256) void k_dgemm(
    const unsigned short* __restrict__ A,
    const unsigned short* __restrict__ BT,
    const float* __restrict__ bias,
    const float* __restrict__ gains,
    float* __restrict__ C)
{
  __shared__ __align__(16) unsigned short As[128*40];
  __shared__ __align__(16) unsigned short Bs[128*40];
  const int tid  = threadIdx.x;
  const int lane = tid & 63;
  const int wave = tid >> 6;
  const int wm = (wave >> 1) * 64;
  const int wn = (wave & 1) * 64;
  const int bm = blockIdx.y * 128;
  const int bn = blockIdx.x * 128;
  const int fml = lane & 15;
  const int q  = lane >> 4;
  const int r0a  = tid >> 2;
  const int sseg = tid & 3;

  f32x4 acc[4][4] = {};

  for (int k0 = 0; k0 < H_; k0 += 32) {
    #pragma unroll
    for (int half = 0; half < 2; ++half) {
      int r = r0a + half*64;
      *(uint4*)(&As[r*40 + sseg*8]) = *(const uint4*)(A + (size_t)(bm + r)*H_ + k0 + sseg*8);
      *(uint4*)(&Bs[r*40 + sseg*8]) = *(const uint4*)(BT + (size_t)(bn + r)*H_ + k0 + sseg*8);
    }
    __syncthreads();
    bf16x8 af[4], bfr[4];
    #pragma unroll
    for (int i = 0; i < 4; ++i)
      af[i] = *(const bf16x8*)(&As[(wm + i*16 + fml)*40 + q*8]);
    #pragma unroll
    for (int j = 0; j < 4; ++j)
      bfr[j] = *(const bf16x8*)(&Bs[(wn + j*16 + fml)*40 + q*8]);
    #pragma unroll
    for (int i = 0; i < 4; ++i)
      #pragma unroll
      for (int j = 0; j < 4; ++j)
        acc[i][j] = __builtin_amdgcn_mfma_f32_16x16x32_bf16(af[i], bfr[j], acc[i][j], 0, 0, 0);
    __syncthreads();
  }
  #pragma unroll
  for (int i = 0; i < 4; ++i) {
    #pragma unroll
    for (int j = 0; j < 4; ++j) {
      int col = bn + wn + j*16 + fml;
      float bv = bias[col];
      #pragma unroll
      for (int r = 0; r < 4; ++r) {
        int row = bm + wm + i*16 + q*4 + r;   // C/D: col=lane&15, row=quad*4+reg
        C[(size_t)row*D_ + col] = gains[row]*acc[i][j][r] + bv;
      }
    }
  }
}

// ---------------------------------------------------------------- layernorm D=1024 in-place — identical to R6
__global__ __launch_bounds__(256) void k_ln(float* __restrict__ X,
    const float* __restrict__ g, const float* __restrict__ b)
{
  const int n = blockIdx.x, tid = threadIdx.x;
  float4* row = (float4*)(X + (size_t)n*D_);
  const float4 xv = row[tid];
  float xa[4] = {xv.x, xv.y, xv.z, xv.w};
  float s = xa[0]+xa[1]+xa[2]+xa[3];
  float ss = xa[0]*xa[0]+xa[1]*xa[1]+xa[2]*xa[2]+xa[3]*xa[3];
  #pragma unroll
  for (int off = 32; off >= 1; off >>= 1) {
    s  += __shfl_down(s, off);
    ss += __shfl_down(ss, off);
  }
  __shared__ float rs[4], rss[4];
  const int lane = tid & 63, wv = tid >> 6;
  if (lane == 0) { rs[wv] = s; rss[wv] = ss; }
  __syncthreads();
  float S0 = rs[0]+rs[1]+rs[2]+rs[3];
  float SS = rss[0]+rss[1]+rss[2]+rss[3];
  float mu = S0 * (1.f/(float)D_);
  float var = SS * (1.f/(float)D_) - mu*mu;
  float inv = rsqrtf(var + 1e-5f);
  int idx = tid*4;
  float4 o;
  o.x = (xa[0]-mu)*inv*g[idx+0] + b[idx+0];
  o.y = (xa[1]-mu)*inv*g[idx+1] + b[idx+1];
  o.z = (xa[2]-mu)*inv*g[idx+2] + b[idx+2];
  o.w = (xa[3]-mu)*inv*g[idx+3] + b[idx+3];
  row[tid] = o;
}

// ----------------------------------------------------------------
// ws layout (common, 9.3 MiB):
//   [0x000000,0x200000) cont f32[8192][64]
//   [0x400000,0x800000) eout f32[16384][64] (slot-indexed, no atomics)
//   0x800000 gains 32K | 0x808000 cnt | 0x809000 list 256K | 0x849000 lw 256K
//   [0x890000,0x8D0000) vinit double[32768]
// Path A (MFMA dec) adds: decWT bf16 [1024][2048] @0x900000 (4 MiB),
//   rates bf16 [T][2048] @0xD00000 (T*4 KiB). T=8192 needs 45.6M, T=4096 29.6M.
// Fallback B: ratSf f32[4096][256] overlays [0,0x400000) (cont dead by then).
// Enc scratch cur f32[8192][1024] = 32 MiB lives in d_out (2 H-chunks).
extern "C" void kernel_launch(void* const* d_in, const int* in_sizes, int n_in,
                              void* d_out, int out_size, void* d_ws, size_t ws_size,
                              hipStream_t stream) {
  (void)in_sizes; (void)n_in; (void)out_size;
  const float* embeds = (const float*)d_in[0];
  const int*   ids    = (const int*)d_in[1];
  const float* pros   = (const float*)d_in[2];
  const float* enc_W  = (const float*)d_in[3];
  const float* enc_b  = (const float*)d_in[4];
  const float* s2c_W  = (const float*)d_in[5];
  const float* s2c_b  = (const float*)d_in[6];
  const float* r_W1   = (const float*)d_in[7];
  const float* r_b1   = (const float*)d_in[8];
  const float* r_W2   = (const float*)d_in[9];
  const float* r_b2   = (const float*)d_in[10];
  const float* e_W1   = (const float*)d_in[11];
  const float* e_b1   = (const float*)d_in[12];
  const float* e_W2   = (const float*)d_in[13];
  const float* e_b2   = (const float*)d_in[14];
  const float* c2s_W  = (const float*)d_in[15];
  const float* c2s_b  = (const float*)d_in[16];
  const float* dec_W  = (const float*)d_in[17];
  const float* dec_b  = (const float*)d_in[18];
  const float* ln_g   = (const float*)d_in[19];
  const float* ln_b   = (const float*)d_in[20];

  char* ws = (char*)d_ws;
  float*          contp = (float*)ws;
  float*          eout  = (float*)(ws + (size_t)0x400000);
  float*          gains = (float*)(ws + (size_t)0x800000);
  int*            cnt   = (int*)(ws + (size_t)0x808000);
  unsigned int*   list  = (unsigned int*)(ws + (size_t)0x809000);
  float*          lw    = (float*)(ws + (size_t)0x849000);
  double*         vinit = (double*)(ws + (size_t)0x890000);
  unsigned short* decWT = (unsigned short*)(ws + (size_t)0x900000);
  unsigned short* rates = (unsigned short*)(ws + (size_t)0xD00000);
  float*          ratSf = (float*)ws;             // fallback overlay of cont
  float*          cur   = (float*)d_out;          // enc scratch [8192][1024]

  const int T = (ws_size >= (size_t)46*1024*1024) ? 8192
              : (ws_size >= (size_t)30*1024*1024) ? 4096 : 0;

  k_gains<<<N_TOK/256, 256, 0, stream>>>(ids, pros, gains);
  k_zero<<<1, 64, 0, stream>>>(cnt);

  // ---- encoder: 2 H-chunks of 1024, bit-identical math to R6's 4x512 ----
  for (int c = 0; c < 2; ++c) {
    k_genc<<<dim3(8, 64), 256, 0, stream>>>(
        embeds, D_, enc_W, H_, c*1024, enc_b, gains, cur, 1024, D_, 3);
    k_gif_warm<<<dim3(16, 8), 256, 0, stream>>>(cur, vinit, 1024, 256, S_);
    k_gif_emit<<<dim3(16, 8), 256, 0, stream>>>(cur, vinit, 1024, 256, S_);
    for (int sub = 0; sub < 2; ++sub) {
      int cc = c*2 + sub;
      k_s2c<<<N_TOK/64, 256, 0, stream>>>(cur + sub*512, 1024, 512,
          s2c_W, (size_t)cc*512*64, contp, (cc > 0));
    }
  }

  k_router<<<N_TOK/256, 256, 0, stream>>>(contp, s2c_b, r_W1, r_b1, r_W2, r_b2,
                                          gains, cnt, list, lw);
  k_expgrp<<<dim3(128, 8), 256, 0, stream>>>(contp, list, lw, cnt,
                                             e_W1, e_b1, e_W2, e_b2, eout);

  if (T > 0) {
    // ---- decoder path A: bf16 MFMA, chunks of T tokens ----
    k_transb<<<dim3(32, 64), 256, 0, stream>>>(dec_W, decWT, H_, D_);
    for (int tok0 = 0; tok0 < N_TOK; tok0 += T) {
      k_c2sB<<<dim3(T/8, 8), 256, 0, stream>>>(eout + (size_t)tok0*128,
          c2s_W, c2s_b, rates);
      float* cur2 = (float*)d_out + (size_t)tok0*D_;
      k_dgemm<<<dim3(D_/128, T/128), 256, 0, stream>>>(
          rates, decWT, dec_b, gains + tok0, cur2);
      int channels = (T/2048)*1024;
      k_gif_warm<<<dim3(channels/256, 8), 256, 0, stream>>>(cur2, vinit, D_, 256, S_);
      k_gif_emit<<<dim3(channels/256, 8), 256, 0, stream>>>(cur2, vinit, D_, 256, S_);
      k_ln<<<T, 256, 0, stream>>>(cur2, ln_g, ln_b);
    }
  } else {
    // ---- decoder fallback (R6 structure): f32 SIMT, 2 halves x 8 K-slices ----
    for (int hb = 0; hb < 2; ++hb) {
      float* cur2 = (float*)d_out + (size_t)hb*4096*D_;
      for (int kh = 0; kh < 8; ++kh) {
        k_c2sS<<<4096/8, 256, 0, stream>>>(eout + (size_t)hb*4096*128,
            c2s_W, kh*256, c2s_b, ratSf);
        int mode = (kh == 0) ? 0 : ((kh < 7) ? 1 : 2);
        k_genc<<<dim3(8, 32), 256, 0, stream>>>(
            ratSf, 256, dec_W + (size_t)kh*256*D_, D_, 0, dec_b,
            gains + hb*4096, cur2, D_, 256, mode);
      }
      k_gif_warm<<<dim3(8, 8), 256, 0, stream>>>(cur2, vinit, D_, 256, S_);
      k_gif_emit<<<dim3(8, 8), 256, 0, stream>>>(cur2, vinit, D_, 256, S_);
      k_ln<<<4096, 256, 0, stream>>>(cur2, ln_g, ln_b);
    }
  }
}

// Round 8
// 1174.833 us; speedup vs baseline: 2.4142x; 1.3998x over previous
//
#include <hip/hip_runtime.h>
#include <math.h>

#define B_ 4
#define S_ 2048
#define D_ 1024
#define H_ 2048
#define N_TOK 8192
#define HALO 256
#define VOCAB_ 32000

typedef short bf16x8 __attribute__((ext_vector_type(8)));
typedef float f32x4 __attribute__((ext_vector_type(4)));

__device__ __forceinline__ float sigf(float x) {
  return 1.0f / (1.0f + __expf(-x));
}
__device__ __forceinline__ float bf2f(unsigned short u) {
  union { unsigned int i; float f; } x; x.i = ((unsigned int)u) << 16; return x.f;
}
__device__ __forceinline__ unsigned short f2bf(float f) {
  union { float f; unsigned int i; } x; x.f = f;
  unsigned int r = x.i + 0x7fffu + ((x.i >> 16) & 1u);
  return (unsigned short)(r >> 16);
}

// ---------------------------------------------------------------- gains (f64 tanh)
__global__ __launch_bounds__(256) void k_gains(const int* __restrict__ ids,
    const float* __restrict__ table, float* __restrict__ gains) {
  int i = blockIdx.x*256 + threadIdx.x;
  int id = ids[i];
  id = id < 0 ? 0 : (id >= VOCAB_ ? VOCAB_-1 : id);
  gains[i] = (float)(1.0 + tanh((double)table[id]));
}

// ---------------------------------------------------------------- f32 SIMT GEMM (fallback enc/dec) — identical math to R6/R7
__global__ __launch_bounds__(256) void k_genc(
    const float* __restrict__ A, int lda,
    const float* __restrict__ W, int ldw, int c0,
    const float* __restrict__ bias,
    const float* __restrict__ gains,
    float* __restrict__ C, int ldc,
    int K, int mode)
{
  __shared__ float As2[16][132];
  __shared__ float Bs[16][128];
  const int tid = threadIdx.x;
  const int tx = tid & 15;
  const int ty = tid >> 4;
  const int bm = blockIdx.y * 128;
  const int bn = blockIdx.x * 128;

  double acc[8][8];
  float part[8][8];
  #pragma unroll
  for (int i = 0; i < 8; ++i)
    #pragma unroll
    for (int j = 0; j < 8; ++j) { acc[i][j] = 0.0; part[i][j] = 0.f; }

  const int e = tid * 8;
  const int ar = e >> 4, ak = e & 15;
  const int bk = e >> 7, bc = e & 127;

  for (int k0 = 0; k0 < K; k0 += 16) {
    {
      const float* pa = A + (size_t)(bm + ar)*lda + k0 + ak;
      float4 v0 = *(const float4*)pa;
      float4 v1 = *(const float4*)(pa + 4);
      As2[ak+0][ar] = v0.x; As2[ak+1][ar] = v0.y;
      As2[ak+2][ar] = v0.z; As2[ak+3][ar] = v0.w;
      As2[ak+4][ar] = v1.x; As2[ak+5][ar] = v1.y;
      As2[ak+6][ar] = v1.z; As2[ak+7][ar] = v1.w;
    }
    {
      const float* pw = W + (size_t)(k0 + bk)*ldw + c0 + bn + bc;
      *(float4*)&Bs[bk][bc]   = *(const float4*)pw;
      *(float4*)&Bs[bk][bc+4] = *(const float4*)(pw + 4);
    }
    __syncthreads();
    #pragma unroll
    for (int kk = 0; kk < 16; ++kk) {
      float a8[8], b8[8];
      *(float4*)&a8[0] = *(const float4*)&As2[kk][ty*8];
      *(float4*)&a8[4] = *(const float4*)&As2[kk][ty*8+4];
      *(float4*)&b8[0] = *(const float4*)&Bs[kk][tx*8];
      *(float4*)&b8[4] = *(const float4*)&Bs[kk][tx*8+4];
      #pragma unroll
      for (int i = 0; i < 8; ++i)
        #pragma unroll
        for (int j = 0; j < 8; ++j)
          part[i][j] += a8[i]*b8[j];
    }
    __syncthreads();
    #pragma unroll
    for (int i = 0; i < 8; ++i)
      #pragma unroll
      for (int j = 0; j < 8; ++j) { acc[i][j] += (double)part[i][j]; part[i][j] = 0.f; }
  }

  #pragma unroll
  for (int i = 0; i < 8; ++i) {
    const int row = bm + ty*8 + i;
    const double g = (mode >= 2) ? (double)gains[row] : 0.0;
    #pragma unroll
    for (int j = 0; j < 8; ++j) {
      const int col = bn + tx*8 + j;
      const size_t idx = (size_t)row*ldc + col;
      if (mode == 0)      C[idx] = (float)acc[i][j];
      else if (mode == 1) C[idx] += (float)acc[i][j];
      else if (mode == 2) C[idx] = (float)(g*((double)C[idx] + acc[i][j]) + (double)bias[c0+col]);
      else                C[idx] = (float)(g*acc[i][j] + (double)bias[c0+col]);
    }
  }
}

// ---------------------------------------------------------------- transpose+split enc_W [1024][2048] f32 -> WhT/WlT [2048][1024] bf16
__global__ __launch_bounds__(256) void k_splitT(const float* __restrict__ in,
    unsigned short* __restrict__ outh, unsigned short* __restrict__ outl) {
  __shared__ unsigned short th[32][33];
  __shared__ unsigned short tl[32][33];
  int c0 = blockIdx.x*32, r0 = blockIdx.y*32;
  int tx = threadIdx.x & 31, ty = threadIdx.x >> 5;
  #pragma unroll
  for (int i = 0; i < 32; i += 8) {
    float x = in[(size_t)(r0+ty+i)*H_ + (c0+tx)];
    unsigned short h = f2bf(x);
    th[ty+i][tx] = h;
    tl[ty+i][tx] = f2bf(x - bf2f(h));
  }
  __syncthreads();
  #pragma unroll
  for (int i = 0; i < 32; i += 8) {
    outh[(size_t)(c0+ty+i)*D_ + (r0+tx)] = th[tx][ty+i];
    outl[(size_t)(c0+ty+i)*D_ + (r0+tx)] = tl[tx][ty+i];
  }
}

// ---------------------------------------------------------------- enc MFMA GEMM, split-bf16 (3 products), in-kernel A split
// C[8192][1024] = gains[m]*(embeds[8192][1024] @ (Bh+Bl)[1024rows][1024]^T) + bias
__global__ __launch_bounds__(256) void k_egemm(
    const float* __restrict__ A,              // embeds f32 [8192][1024]
    const unsigned short* __restrict__ Bh,    // WhT + chunk offset, [1024][1024] bf16
    const unsigned short* __restrict__ Bl,
    const float* __restrict__ bias,           // enc_b + chunk offset
    const float* __restrict__ gains,
    float* __restrict__ C)                    // cur [8192][1024]
{
  __shared__ __align__(16) unsigned short Ahs[128*40];
  __shared__ __align__(16) unsigned short Als[128*40];
  __shared__ __align__(16) unsigned short Bhs[128*40];
  __shared__ __align__(16) unsigned short Bls[128*40];
  const int tid  = threadIdx.x;
  const int lane = tid & 63;
  const int wave = tid >> 6;
  const int wm = (wave >> 1) * 64;
  const int wn = (wave & 1) * 64;
  const int bm = blockIdx.y * 128;
  const int bn = blockIdx.x * 128;
  const int fml = lane & 15;
  const int q  = lane >> 4;
  const int r0a  = tid >> 2;
  const int sseg = tid & 3;

  f32x4 acc[4][4] = {};

  for (int k0 = 0; k0 < 1024; k0 += 32) {
    #pragma unroll
    for (int half = 0; half < 2; ++half) {
      int r = r0a + half*64;
      const float* pa = A + (size_t)(bm + r)*1024 + k0 + sseg*8;
      float4 v0 = *(const float4*)pa;
      float4 v1 = *(const float4*)(pa + 4);
      float xs[8] = {v0.x, v0.y, v0.z, v0.w, v1.x, v1.y, v1.z, v1.w};
      unsigned int hp[4], lp[4];
      #pragma unroll
      for (int t = 0; t < 4; ++t) {
        unsigned short h0 = f2bf(xs[2*t]);
        unsigned short h1 = f2bf(xs[2*t+1]);
        unsigned short l0 = f2bf(xs[2*t]   - bf2f(h0));
        unsigned short l1 = f2bf(xs[2*t+1] - bf2f(h1));
        hp[t] = (unsigned)h0 | ((unsigned)h1 << 16);
        lp[t] = (unsigned)l0 | ((unsigned)l1 << 16);
      }
      *(uint4*)(&Ahs[r*40 + sseg*8]) = make_uint4(hp[0], hp[1], hp[2], hp[3]);
      *(uint4*)(&Als[r*40 + sseg*8]) = make_uint4(lp[0], lp[1], lp[2], lp[3]);
      *(uint4*)(&Bhs[r*40 + sseg*8]) = *(const uint4*)(Bh + (size_t)(bn + r)*1024 + k0 + sseg*8);
      *(uint4*)(&Bls[r*40 + sseg*8]) = *(const uint4*)(Bl + (size_t)(bn + r)*1024 + k0 + sseg*8);
    }
    __syncthreads();
    bf16x8 afh[4], afl[4], bfh[4], bfl[4];
    #pragma unroll
    for (int i = 0; i < 4; ++i) {
      afh[i] = *(const bf16x8*)(&Ahs[(wm + i*16 + fml)*40 + q*8]);
      afl[i] = *(const bf16x8*)(&Als[(wm + i*16 + fml)*40 + q*8]);
    }
    #pragma unroll
    for (int j = 0; j < 4; ++j) {
      bfh[j] = *(const bf16x8*)(&Bhs[(wn + j*16 + fml)*40 + q*8]);
      bfl[j] = *(const bf16x8*)(&Bls[(wn + j*16 + fml)*40 + q*8]);
    }
    #pragma unroll
    for (int i = 0; i < 4; ++i)
      #pragma unroll
      for (int j = 0; j < 4; ++j) {
        acc[i][j] = __builtin_amdgcn_mfma_f32_16x16x32_bf16(afl[i], bfh[j], acc[i][j], 0, 0, 0);
        acc[i][j] = __builtin_amdgcn_mfma_f32_16x16x32_bf16(afh[i], bfl[j], acc[i][j], 0, 0, 0);
        acc[i][j] = __builtin_amdgcn_mfma_f32_16x16x32_bf16(afh[i], bfh[j], acc[i][j], 0, 0, 0);
      }
    __syncthreads();
  }
  #pragma unroll
  for (int i = 0; i < 4; ++i) {
    #pragma unroll
    for (int j = 0; j < 4; ++j) {
      int col = bn + wn + j*16 + fml;
      float bv = bias[col];
      #pragma unroll
      for (int r = 0; r < 4; ++r) {
        int row = bm + wm + i*16 + q*4 + r;   // C/D: col=lane&15, row=quad*4+reg
        C[(size_t)row*D_ + col] = gains[row]*acc[i][j][r] + bv;
      }
    }
  }
}

// ---------------------------------------------------------------- GIF scan, f64 membrane — identical math to R6
__global__ __launch_bounds__(256) void k_gif_warm(const float* __restrict__ buf,
    double* __restrict__ vinit, int Wd, int CS, int Stot)
{
  int c = blockIdx.x*256 + threadIdx.x;
  int channels = gridDim.x*256;
  int chunk = blockIdx.y;
  int b = c / Wd, h = c - b*Wd;
  int s_emit = chunk*CS;
  int s0 = s_emit - HALO; if (s0 < 0) s0 = 0;
  const float* p = buf + (size_t)b*Stot*Wd + h;
  double v = 0.0;
  for (int sg = s0; sg < s_emit; sg += 8) {
    float cv[8];
    #pragma unroll
    for (int i = 0; i < 8; ++i) cv[i] = p[(size_t)(sg+i)*Wd];
    #pragma unroll
    for (int i = 0; i < 8; ++i) {
      v = 0.9*v + (double)cv[i];
      double s = 1.0/(1.0 + exp(-4.0*(v - 1.0)));
      v -= s;
    }
  }
  vinit[(size_t)chunk*channels + c] = v;
}

__global__ __launch_bounds__(256) void k_gif_emit(float* __restrict__ buf,
    const double* __restrict__ vinit, int Wd, int CS, int Stot)
{
  int c = blockIdx.x*256 + threadIdx.x;
  int channels = gridDim.x*256;
  int chunk = blockIdx.y;
  int b = c / Wd, h = c - b*Wd;
  float* p = buf + (size_t)b*Stot*Wd + h + (size_t)chunk*CS*Wd;
  double v = vinit[(size_t)chunk*channels + c];
  float cv[8], nv[8] = {0,0,0,0,0,0,0,0};
  #pragma unroll
  for (int i = 0; i < 8; ++i) cv[i] = p[(size_t)i*Wd];
  for (int sg = 0; sg < CS; sg += 8) {
    float sp[8];
    #pragma unroll
    for (int i = 0; i < 8; ++i) {
      v = 0.9*v + (double)cv[i];
      double s = 1.0/(1.0 + exp(-4.0*(v - 1.0)));
      v -= s; sp[i] = (float)s;
    }
    if (sg + 8 < CS) {
      #pragma unroll
      for (int i = 0; i < 8; ++i) nv[i] = p[(size_t)(sg+8+i)*Wd];
    }
    #pragma unroll
    for (int i = 0; i < 8; ++i) p[(size_t)(sg+i)*Wd] = sp[i];
    #pragma unroll
    for (int i = 0; i < 8; ++i) cv[i] = nv[i];
  }
}

// ---------------------------------------------------------------- s2c partial, f64 FMA — identical math to R7
__global__ __launch_bounds__(256) void k_s2c(const float* __restrict__ Sp, int ldS, int KH,
    const float* __restrict__ W, size_t woff, float* __restrict__ out, int accum) {
  __shared__ float As_[64][17];
  __shared__ float Ws_[16][68];
  const int bm = blockIdx.x * 64;
  const int tid = threadIdx.x;
  const int rt = tid >> 4;
  const int ct = tid & 15;
  double acc[4][4] = {};
  for (int k0 = 0; k0 < KH; k0 += 16) {
    #pragma unroll
    for (int i = 0; i < 4; ++i) {
      int e = tid + i*256;
      As_[e >> 4][e & 15] = Sp[(size_t)(bm + (e >> 4))*ldS + k0 + (e & 15)];
    }
    #pragma unroll
    for (int i = 0; i < 4; ++i) {
      int e = tid + i*256;
      Ws_[e >> 6][e & 63] = W[woff + (size_t)(k0 + (e >> 6))*64 + (e & 63)];
    }
    __syncthreads();
    #pragma unroll
    for (int kk = 0; kk < 16; ++kk) {
      double a4[4], b4[4];
      #pragma unroll
      for (int i = 0; i < 4; ++i) a4[i] = (double)As_[rt*4+i][kk];
      #pragma unroll
      for (int j = 0; j < 4; ++j) b4[j] = (double)Ws_[kk][ct*4+j];
      #pragma unroll
      for (int i = 0; i < 4; ++i)
        #pragma unroll
        for (int j = 0; j < 4; ++j) acc[i][j] += a4[i]*b4[j];
    }
    __syncthreads();
  }
  #pragma unroll
  for (int i = 0; i < 4; ++i)
    #pragma unroll
    for (int j = 0; j < 4; ++j) {
      size_t idx = ((size_t)bm + rt*4+i)*64 + ct*4+j;
      float a = (float)acc[i][j];
      if (accum) out[idx] += a; else out[idx] = a;
    }
}

// ---------------------------------------------------------------- zero expert counters
__global__ void k_zero(int* p) { if (threadIdx.x < 8) p[threadIdx.x] = 0; }

// ---------------------------------------------------------------- router: f64 logits + per-expert list append — identical to R7
__global__ __launch_bounds__(256) void k_router(float* __restrict__ contp,
    const float* __restrict__ s2c_b,
    const float* __restrict__ rW1, const float* __restrict__ rb1,
    const float* __restrict__ rW2, const float* __restrict__ rb2,
    const float* __restrict__ gains,
    int* __restrict__ cnt, unsigned int* __restrict__ list, float* __restrict__ lw)
{
  __shared__ float W1s[64*64];
  __shared__ float W2s[64*8];
  __shared__ float b1s[64];
  __shared__ float b2s[8];
  __shared__ float sbl[64];
  const int tid = threadIdx.x;
  const int n = blockIdx.x*256 + tid;
  for (int i = tid; i < 64*64; i += 256) W1s[i] = rW1[i];
  for (int i = tid; i < 64*8; i += 256)  W2s[i] = rW2[i];
  if (tid < 64) { b1s[tid] = rb1[tid]; sbl[tid] = s2c_b[tid]; }
  if (tid < 8)  b2s[tid] = rb2[tid];
  __syncthreads();

  float c[64];
  {
    float4* pA = (float4*)(contp + (size_t)n*64);
    #pragma unroll
    for (int m4 = 0; m4 < 16; ++m4) {
      float4 a = pA[m4];
      float4 o;
      o.x = a.x + sbl[m4*4+0];
      o.y = a.y + sbl[m4*4+1];
      o.z = a.z + sbl[m4*4+2];
      o.w = a.w + sbl[m4*4+3];
      c[m4*4+0] = o.x; c[m4*4+1] = o.y; c[m4*4+2] = o.z; c[m4*4+3] = o.w;
      pA[m4] = o;
    }
  }
  double lg[8];
  #pragma unroll
  for (int e = 0; e < 8; ++e) lg[e] = (double)b2s[e];
  for (int j = 0; j < 64; ++j) {
    double t = (double)b1s[j];
    #pragma unroll
    for (int m = 0; m < 64; ++m) t += (double)c[m]*(double)W1s[m*64 + j];
    t = tanh(t);
    #pragma unroll
    for (int e = 0; e < 8; ++e) lg[e] += t * (double)W2s[j*8 + e];
  }
  double g = (double)gains[n];
  #pragma unroll
  for (int e = 0; e < 8; ++e) lg[e] *= g;
  int i1 = 0; double m1 = lg[0];
  #pragma unroll
  for (int e = 1; e < 8; ++e) if (lg[e] > m1) { m1 = lg[e]; i1 = e; }
  int i2 = (i1 == 0) ? 1 : 0; double m2 = lg[i2];
  #pragma unroll
  for (int e = 0; e < 8; ++e) if (e != i1 && lg[e] > m2) { m2 = lg[e]; i2 = e; }
  float w1 = (float)(1.0 / (1.0 + exp(m2 - m1)));
  int p1 = atomicAdd(&cnt[i1], 1);
  list[i1*8192 + p1] = ((unsigned)n << 1);
  lw[i1*8192 + p1] = w1;
  int p2 = atomicAdd(&cnt[i2], 1);
  list[i2*8192 + p2] = ((unsigned)n << 1) | 1u;
  lw[i2*8192 + p2] = 1.0f - w1;
}

// ---------------------------------------------------------------- grouped experts — identical to R7
__global__ __launch_bounds__(256) void k_expgrp(
    const float* __restrict__ cont,
    const unsigned int* __restrict__ list, const float* __restrict__ lw,
    const int* __restrict__ cnt,
    const float* __restrict__ eW1, const float* __restrict__ eb1,
    const float* __restrict__ eW2, const float* __restrict__ eb2,
    float* __restrict__ eout)
{
  const int e = blockIdx.y;
  const int t0 = blockIdx.x * 64;
  const int ce = cnt[e];
  if (t0 >= ce) return;
  const int nt = (ce - t0 < 64) ? (ce - t0) : 64;
  __shared__ float ct[64][65];
  __shared__ float w1b[64][65];
  __shared__ float hbl[64][65];
  __shared__ float w2b[64][65];
  __shared__ unsigned int sl[64];
  __shared__ float swt[64];
  const int tid = threadIdx.x;
  if (tid < 64) {
    if (tid < nt) {
      sl[tid]  = list[e*8192 + t0 + tid];
      swt[tid] = lw[e*8192 + t0 + tid];
    } else { sl[tid] = 0; swt[tid] = 0.f; }
  }
  __syncthreads();
  for (int f = tid; f < 64*64; f += 256) {
    int r = f >> 6, m = f & 63;
    ct[r][m] = (r < nt) ? cont[(size_t)(sl[r] >> 1)*64 + m] : 0.f;
  }
  const float* W1 = eW1 + (size_t)e*64*1024;
  const float* W2 = eW2 + (size_t)e*1024*64;
  const float* B1 = eb1 + (size_t)e*1024;
  const int rt = tid >> 4, c16 = tid & 15;
  float outa[4][4] = {};
  for (int hc = 0; hc < 1024; hc += 64) {
    __syncthreads();
    for (int f = tid; f < 64*64; f += 256) {
      int m = f >> 6, j = f & 63;
      w1b[m][j] = W1[(size_t)m*1024 + hc + j];
      w2b[m][j] = W2[(size_t)(hc + m)*64 + j];
    }
    __syncthreads();
    float h4[4][4];
    #pragma unroll
    for (int i = 0; i < 4; ++i) {
      #pragma unroll
      for (int j = 0; j < 4; ++j) h4[i][j] = B1[hc + c16*4 + j];
    }
    #pragma unroll 16
    for (int m = 0; m < 64; ++m) {
      float a4[4], b4[4];
      #pragma unroll
      for (int i = 0; i < 4; ++i) a4[i] = ct[rt*4+i][m];
      #pragma unroll
      for (int j = 0; j < 4; ++j) b4[j] = w1b[m][c16*4+j];
      #pragma unroll
      for (int i = 0; i < 4; ++i)
        #pragma unroll
        for (int j = 0; j < 4; ++j) h4[i][j] += a4[i]*b4[j];
    }
    #pragma unroll
    for (int i = 0; i < 4; ++i)
      #pragma unroll
      for (int j = 0; j < 4; ++j)
        hbl[rt*4+i][c16*4+j] = fmaxf(h4[i][j], 0.f);
    __syncthreads();
    #pragma unroll 16
    for (int j = 0; j < 64; ++j) {
      float a4[4], b4[4];
      #pragma unroll
      for (int i = 0; i < 4; ++i) a4[i] = hbl[rt*4+i][j];
      #pragma unroll
      for (int nn = 0; nn < 4; ++nn) b4[nn] = w2b[j][c16*4+nn];
      #pragma unroll
      for (int i = 0; i < 4; ++i)
        #pragma unroll
        for (int nn = 0; nn < 4; ++nn) outa[i][nn] += a4[i]*b4[nn];
    }
  }
  #pragma unroll
  for (int i = 0; i < 4; ++i) {
    int r = rt*4 + i;
    if (r < nt) {
      float w = swt[r];
      #pragma unroll
      for (int nn = 0; nn < 4; ++nn) {
        int col = c16*4 + nn;
        eout[(size_t)sl[r]*64 + col] = w * (outa[i][nn] + eb2[(size_t)e*64 + col]);
      }
    }
  }
}

// ---------------------------------------------------------------- c2s -> bf16 rates, 64 tokens/block (8x less W traffic)
__global__ __launch_bounds__(256) void k_c2sB(const float* __restrict__ eoutTok,
    const float* __restrict__ W, const float* __restrict__ bias,
    unsigned short* __restrict__ rates)
{
  __shared__ float ml[64][64];
  const int tid = threadIdx.x;
  const int n0 = blockIdx.x * 64;
  const int coff = blockIdx.y * 256;
  for (int i = tid; i < 64*64; i += 256) {
    int t = i >> 6, m = i & 63;
    ml[t][m] = eoutTok[(size_t)(n0+t)*128 + m] + eoutTok[(size_t)(n0+t)*128 + 64 + m];
  }
  __syncthreads();
  float acc[64];
  #pragma unroll
  for (int t = 0; t < 64; ++t) acc[t] = 0.f;
  for (int m = 0; m < 64; ++m) {
    float wv = W[(size_t)m*H_ + coff + tid];
    #pragma unroll
    for (int t = 0; t < 64; ++t) acc[t] += ml[t][m] * wv;
  }
  float bv = bias[coff + tid];
  #pragma unroll
  for (int t = 0; t < 64; ++t)
    rates[(size_t)(n0+t)*H_ + coff + tid] = f2bf(sigf(acc[t] + bv));
}

// ---------------------------------------------------------------- c2s 256-col slice -> f32 (fallback path)
__global__ __launch_bounds__(256) void k_c2sS(const float* __restrict__ eoutTok,
    const float* __restrict__ W, int coff,
    const float* __restrict__ bias, float* __restrict__ rat)
{
  __shared__ float ml[8][64];
  const int tid = threadIdx.x;
  const int n0 = blockIdx.x * 8;
  for (int i = tid; i < 512; i += 256) {
    int t = i >> 6, m = i & 63;
    ml[t][m] = eoutTok[(size_t)(n0+t)*128 + m] + eoutTok[(size_t)(n0+t)*128 + 64 + m];
  }
  __syncthreads();
  float acc[8] = {};
  for (int m = 0; m < 64; ++m) {
    float wv = W[(size_t)m*H_ + coff + tid];
    #pragma unroll
    for (int t = 0; t < 8; ++t) acc[t] += ml[t][m] * wv;
  }
  float bv = bias[coff + tid];
  #pragma unroll
  for (int t = 0; t < 8; ++t)
    rat[(size_t)(n0+t)*256 + tid] = sigf(acc[t] + bv);
}

// ---------------------------------------------------------------- f32 -> bf16 transpose (dec_W [R][C] -> out [C][R])
__global__ __launch_bounds__(256) void k_transb(const float* __restrict__ in,
    unsigned short* __restrict__ out, int R, int C) {
  __shared__ unsigned short t[32][33];
  int c0 = blockIdx.x*32, r0 = blockIdx.y*32;
  int tx = threadIdx.x & 31, ty = threadIdx.x >> 5;
  #pragma unroll
  for (int i = 0; i < 32; i += 8)
    t[ty+i][tx] = f2bf(in[(size_t)(r0+ty+i)*C + (c0+tx)]);
  __syncthreads();
  #pragma unroll
  for (int i = 0; i < 32; i += 8)
    out[(size_t)(c0+ty+i)*R + (r0+tx)] = t[tx][ty+i];
}

// ---------------------------------------------------------------- dec MFMA GEMM — identical to R7
__global__ __launch_bounds__(256) void k_dgemm(
    const unsigned short* __restrict__ A,
    const unsigned short* __restrict__ BT,
    const float* __restrict__ bias,
    const float* __restrict__ gains,
    float* __restrict__ C)
{
  __shared__ __align__(16) unsigned short As[128*40];
  __shared__ __align__(16) unsigned short Bs[128*40];
  const int tid  = threadIdx.x;
  const int lane = tid & 63;
  const int wave = tid >> 6;
  const int wm = (wave >> 1) * 64;
  const int wn = (wave & 1) * 64;
  const int bm = blockIdx.y * 128;
  const int bn = blockIdx.x * 128;
  const int fml = lane & 15;
  const int q  = lane >> 4;
  const int r0a  = tid >> 2;
  const int sseg = tid & 3;

  f32x4 acc[4][4] = {};

  for (int k0 = 0; k0 < H_; k0 += 32) {
    #pragma unroll
    for (int half = 0; half < 2; ++half) {
      int r = r0a + half*64;
      *(uint4*)(&As[r*40 + sseg*8]) = *(const uint4*)(A + (size_t)(bm + r)*H_ + k0 + sseg*8);
      *(uint4*)(&Bs[r*40 + sseg*8]) = *(const uint4*)(BT + (size_t)(bn + r)*H_ + k0 + sseg*8);
    }
    __syncthreads();
    bf16x8 af[4], bfr[4];
    #pragma unroll
    for (int i = 0; i < 4; ++i)
      af[i] = *(const bf16x8*)(&As[(wm + i*16 + fml)*40 + q*8]);
    #pragma unroll
    for (int j = 0; j < 4; ++j)
      bfr[j] = *(const bf16x8*)(&Bs[(wn + j*16 + fml)*40 + q*8]);
    #pragma unroll
    for (int i = 0; i < 4; ++i)
      #pragma unroll
      for (int j = 0; j < 4; ++j)
        acc[i][j] = __builtin_amdgcn_mfma_f32_16x16x32_bf16(af[i], bfr[j], acc[i][j], 0, 0, 0);
    __syncthreads();
  }
  #pragma unroll
  for (int i = 0; i < 4; ++i) {
    #pragma unroll
    for (int j = 0; j < 4; ++j) {
      int col = bn + wn + j*16 + fml;
      float bv = bias[col];
      #pragma unroll
      for (int r = 0; r < 4; ++r) {
        int row = bm + wm + i*16 + q*4 + r;
        C[(size_t)row*D_ + col] = gains[row]*acc[i][j][r] + bv;
      }
    }
  }
}

// ---------------------------------------------------------------- layernorm D=1024 in-place — identical to R6
__global__ __launch_bounds__(256) void k_ln(float* __restrict__ X,
    const float* __restrict__ g, const float* __restrict__ b)
{
  const int n = blockIdx.x, tid = threadIdx.x;
  float4* row = (float4*)(X + (size_t)n*D_);
  const float4 xv = row[tid];
  float xa[4] = {xv.x, xv.y, xv.z, xv.w};
  float s = xa[0]+xa[1]+xa[2]+xa[3];
  float ss = xa[0]*xa[0]+xa[1]*xa[1]+xa[2]*xa[2]+xa[3]*xa[3];
  #pragma unroll
  for (int off = 32; off >= 1; off >>= 1) {
    s  += __shfl_down(s, off);
    ss += __shfl_down(ss, off);
  }
  __shared__ float rs[4], rss[4];
  const int lane = tid & 63, wv = tid >> 6;
  if (lane == 0) { rs[wv] = s; rss[wv] = ss; }
  __syncthreads();
  float S0 = rs[0]+rs[1]+rs[2]+rs[3];
  float SS = rss[0]+rss[1]+rss[2]+rss[3];
  float mu = S0 * (1.f/(float)D_);
  float var = SS * (1.f/(float)D_) - mu*mu;
  float inv = rsqrtf(var + 1e-5f);
  int idx = tid*4;
  float4 o;
  o.x = (xa[0]-mu)*inv*g[idx+0] + b[idx+0];
  o.y = (xa[1]-mu)*inv*g[idx+1] + b[idx+1];
  o.z = (xa[2]-mu)*inv*g[idx+2] + b[idx+2];
  o.w = (xa[3]-mu)*inv*g[idx+3] + b[idx+3];
  row[tid] = o;
}

// ----------------------------------------------------------------
// ws layout:
//   [0x000000,0x200000) cont f32[8192][64]
//   [0x400000,0x800000) eout f32[16384][64]  (free during enc GEMM)
//   0x800000 gains | 0x808000 cnt | 0x809000 list | 0x849000 lw
//   [0x890000,0x8D0000) vinit double[32768]
//   0x900000 (4 MiB): WhT (enc) -> decWT (dec)      [needs ws>=18 MiB]
//   0xD00000 (4 MiB): WlT (enc) -> rates (dec path A, T*4 KiB)
// All tier choices are host-side on the actual ws_size -> no OOB possible.
// Enc scratch cur f32[8192][1024] = 32 MiB lives in d_out (2 H-chunks).
extern "C" void kernel_launch(void* const* d_in, const int* in_sizes, int n_in,
                              void* d_out, int out_size, void* d_ws, size_t ws_size,
                              hipStream_t stream) {
  (void)in_sizes; (void)n_in; (void)out_size;
  const float* embeds = (const float*)d_in[0];
  const int*   ids    = (const int*)d_in[1];
  const float* pros   = (const float*)d_in[2];
  const float* enc_W  = (const float*)d_in[3];
  const float* enc_b  = (const float*)d_in[4];
  const float* s2c_W  = (const float*)d_in[5];
  const float* s2c_b  = (const float*)d_in[6];
  const float* r_W1   = (const float*)d_in[7];
  const float* r_b1   = (const float*)d_in[8];
  const float* r_W2   = (const float*)d_in[9];
  const float* r_b2   = (const float*)d_in[10];
  const float* e_W1   = (const float*)d_in[11];
  const float* e_b1   = (const float*)d_in[12];
  const float* e_W2   = (const float*)d_in[13];
  const float* e_b2   = (const float*)d_in[14];
  const float* c2s_W  = (const float*)d_in[15];
  const float* c2s_b  = (const float*)d_in[16];
  const float* dec_W  = (const float*)d_in[17];
  const float* dec_b  = (const float*)d_in[18];
  const float* ln_g   = (const float*)d_in[19];
  const float* ln_b   = (const float*)d_in[20];

  char* ws = (char*)d_ws;
  float*          contp = (float*)ws;
  float*          eout  = (float*)(ws + (size_t)0x400000);
  float*          gains = (float*)(ws + (size_t)0x800000);
  int*            cnt   = (int*)(ws + (size_t)0x808000);
  unsigned int*   list  = (unsigned int*)(ws + (size_t)0x809000);
  float*          lw    = (float*)(ws + (size_t)0x849000);
  double*         vinit = (double*)(ws + (size_t)0x890000);
  unsigned short* WhT   = (unsigned short*)(ws + (size_t)0x900000); // -> decWT
  unsigned short* WlT   = (unsigned short*)(ws + (size_t)0xD00000); // -> rates
  unsigned short* decWT = WhT;
  unsigned short* rates = WlT;
  float*          ratSf = (float*)ws;              // fallback overlay of cont
  float*          cur   = (float*)d_out;           // enc scratch [8192][1024]

  const int encM = (ws_size >= (size_t)18*1024*1024) ? 1 : 0;
  const int T = (ws_size >= (size_t)46*1024*1024) ? 8192
              : (ws_size >= (size_t)30*1024*1024) ? 4096 : 0;

  k_gains<<<N_TOK/256, 256, 0, stream>>>(ids, pros, gains);
  k_zero<<<1, 64, 0, stream>>>(cnt);

  // ---- encoder: 2 H-chunks of 1024 ----
  if (encM) {
    k_splitT<<<dim3(64, 32), 256, 0, stream>>>(enc_W, WhT, WlT);
    for (int c = 0; c < 2; ++c) {
      k_egemm<<<dim3(8, 64), 256, 0, stream>>>(
          embeds, WhT + (size_t)c*1024*1024, WlT + (size_t)c*1024*1024,
          enc_b + c*1024, gains, cur);
      k_gif_warm<<<dim3(16, 8), 256, 0, stream>>>(cur, vinit, 1024, 256, S_);
      k_gif_emit<<<dim3(16, 8), 256, 0, stream>>>(cur, vinit, 1024, 256, S_);
      for (int sub = 0; sub < 2; ++sub) {
        int cc = c*2 + sub;
        k_s2c<<<N_TOK/64, 256, 0, stream>>>(cur + sub*512, 1024, 512,
            s2c_W, (size_t)cc*512*64, contp, (cc > 0));
      }
    }
  } else {
    for (int c = 0; c < 2; ++c) {
      k_genc<<<dim3(8, 64), 256, 0, stream>>>(
          embeds, D_, enc_W, H_, c*1024, enc_b, gains, cur, 1024, D_, 3);
      k_gif_warm<<<dim3(16, 8), 256, 0, stream>>>(cur, vinit, 1024, 256, S_);
      k_gif_emit<<<dim3(16, 8), 256, 0, stream>>>(cur, vinit, 1024, 256, S_);
      for (int sub = 0; sub < 2; ++sub) {
        int cc = c*2 + sub;
        k_s2c<<<N_TOK/64, 256, 0, stream>>>(cur + sub*512, 1024, 512,
            s2c_W, (size_t)cc*512*64, contp, (cc > 0));
      }
    }
  }

  k_router<<<N_TOK/256, 256, 0, stream>>>(contp, s2c_b, r_W1, r_b1, r_W2, r_b2,
                                          gains, cnt, list, lw);
  k_expgrp<<<dim3(128, 8), 256, 0, stream>>>(contp, list, lw, cnt,
                                             e_W1, e_b1, e_W2, e_b2, eout);

  if (T > 0) {
    // ---- decoder path A: bf16 MFMA ----
    k_transb<<<dim3(32, 64), 256, 0, stream>>>(dec_W, decWT, H_, D_);
    for (int tok0 = 0; tok0 < N_TOK; tok0 += T) {
      k_c2sB<<<dim3(T/64, 8), 256, 0, stream>>>(eout + (size_t)tok0*128,
          c2s_W, c2s_b, rates);
      float* cur2 = (float*)d_out + (size_t)tok0*D_;
      k_dgemm<<<dim3(D_/128, T/128), 256, 0, stream>>>(
          rates, decWT, dec_b, gains + tok0, cur2);
      int channels = (T/2048)*1024;
      k_gif_warm<<<dim3(channels/256, 8), 256, 0, stream>>>(cur2, vinit, D_, 256, S_);
      k_gif_emit<<<dim3(channels/256, 8), 256, 0, stream>>>(cur2, vinit, D_, 256, S_);
      k_ln<<<T, 256, 0, stream>>>(cur2, ln_g, ln_b);
    }
  } else {
    // ---- decoder fallback: f32 SIMT, 2 halves x 8 K-slices ----
    for (int hb = 0; hb < 2; ++hb) {
      float* cur2 = (float*)d_out + (size_t)hb*4096*D_;
      for (int kh = 0; kh < 8; ++kh) {
        k_c2sS<<<4096/8, 256, 0, stream>>>(eout + (size_t)hb*4096*128,
            c2s_W, kh*256, c2s_b, ratSf);
        int mode = (kh == 0) ? 0 : ((kh < 7) ? 1 : 2);
        k_genc<<<dim3(8, 32), 256, 0, stream>>>(
            ratSf, 256, dec_W + (size_t)kh*256*D_, D_, 0, dec_b,
            gains + hb*4096, cur2, D_, 256, mode);
      }
      k_gif_warm<<<dim3(8, 8), 256, 0, stream>>>(cur2, vinit, D_, 256, S_);
      k_gif_emit<<<dim3(8, 8), 256, 0, stream>>>(cur2, vinit, D_, 256, S_);
      k_ln<<<4096, 256, 0, stream>>>(cur2, ln_g, ln_b);
    }
  }
}